// Round 23
// baseline (123.427 us; speedup 1.0000x reference)
//
#include <hip/hip_runtime.h>

#define HH 1024
#define WW 1024
#define TW 116         // output cols per tile (even -> float2-aligned halo)
#define WLP 144        // colsum slots per row (max touched 141, no clamps)
#define NSLOT 1024     // partial-sum slots (atomic contention spread)
#define SSIM_C1 1e-4f
#define SSIM_C2 9e-4f

typedef float vf2 __attribute__((ext_vector_type(2)));
typedef __fp16 h2 __attribute__((ext_vector_type(2)));
typedef __fp16 h4 __attribute__((ext_vector_type(4)));

__global__ void ssim_ws_init(float* ws) { ws[threadIdx.x] = 0.f; }

// SSIM core for one output column, raw-sum space (u = 1/w):
#define SSIM_EMIT do { \
    const float S1 = (float)win.x, S2 = (float)win.y; \
    const float P  = (float)win.z, Q  = (float)win.w; \
    const float m11 = S1 * S1, m22 = S2 * S2, m12 = S1 * S2; \
    const float sigs = hu * (P + Q) - m11 - m22; \
    const float s12  = qu * (P - Q) - m12; \
    const float num  = (2.f * m12 + C1p) * (2.f * s12 + C2p); \
    const float den  = (m11 + m22 + C1p) * (sigs + C2p); \
    ssum += num * __builtin_amdgcn_rcpf(den); \
} while (0)

// Phase 2 over this wave's slab (two 8-col slides, win carried, v[19] profile)
#define PHASE2 do { if (S > 0) { \
    h4 v[19]; \
    _Pragma("unroll") \
    for (int k = 0; k < 19; ++k) v[k] = cs4[q][r][(c0 + k) ^ r]; \
    __builtin_amdgcn_sched_barrier(0); \
    h4 win = v[1] + v[2]; \
    win += v[3]; win += v[4]; win += v[5]; win += v[6]; \
    win += v[7]; win += v[8]; win += v[9]; win += v[10]; \
    _Pragma("unroll") \
    for (int p = 0; p < 8; ++p) { \
        if (p >= S) break; \
        win += v[p + 11]; SSIM_EMIT; win -= v[p + 1]; \
    } \
    _Pragma("unroll") \
    for (int k = 0; k < 8; ++k) v[k + 1] = cs4[q][r][(c0 + 19 + k) ^ r]; \
    __builtin_amdgcn_sched_barrier(0); \
    _Pragma("unroll") \
    for (int p = 0; p < 8; ++p) { \
        if (p + 8 >= S) break; \
        win += v[p + 1]; SSIM_EMIT; win -= v[p + 9]; \
    } \
} } while (0)

// Wave-autonomous, ring-carried 16-row task: half A loads 18 rows -> colsum
// rows 0..7 -> PHASE2; half B loads ONLY 8 new rows and continues the running
// vertical sums (drops from still-live X[7..14]) -> rows 8..15 -> PHASE2.
// Loads per 16 rows: 52 vs 72 (-28%), one 11-row prologue eliminated.
// Peak live in PHASE2#1: 8 rows (32 VGPR) + v[19] (38) -> fits (256,4)'s 128
// cap (R22's failure held 18 rows = 72 VGPR).
__global__ __launch_bounds__(256, 4) void ssim_main(const float* __restrict__ img1,
                                                    const float* __restrict__ img2,
                                                    const float* __restrict__ window,
                                                    float* __restrict__ ws)
{
    __shared__ h4 cs4[4][8][WLP];    // 36.9 KB; one 8-row slab per wave, reused

    const int tx = blockIdx.x;       // col tile: 0..8
    const int ty = blockIdx.y;       // 64-row band: 0..15
    const int b  = blockIdx.z;       // batch
    const int t  = threadIdx.x;
    const int q  = t >> 6;           // wave 0..3 -> rows ty*64 + q*16 .. +15
    const int cg = t & 63;           // column pair
    const int C0 = tx * TW;
    const int R0 = ty * 64 + q * 16;
    const size_t ibase = (size_t)b * (size_t)(HH * WW);
    const float w = window[0];

    const int gc   = C0 - 6 + 2 * cg;    // even -> 8B-aligned float2
    const bool cin = (tx >= 1) && (tx <= 7);
    const bool cok = (unsigned)gc < (unsigned)WW;
    const int gcc  = min(max(gc, 0), WW - 2);

    // phase-2 constants
    const float u   = __builtin_amdgcn_rcpf(w);   // = 121
    const float hu  = 0.5f  * u;
    const float qu  = 0.25f * u;
    const float C1p = SSIM_C1 * u * u;
    const float C2p = SSIM_C2 * u * u;
    const int r   = cg & 7;
    const int seg = cg >> 3;             // 8 segments x 16 cols
    const int c0  = seg * 16;            // 0..112
    const int TWa = min(TW, WW - C0);    // ragged last col-tile (96)
    const int S   = min(16, TWa - c0);

    float ssum = 0.f;
    vf2 X[18], Y[18];
    vf2 s1 = {0.f, 0.f}, s2 = {0.f, 0.f}, sp = {0.f, 0.f}, sq = {0.f, 0.f};

    // ================= Half A: colsum rows 0..7 (image rows R0-5..R0+12) ====
    {
        const int jb = __builtin_amdgcn_readfirstlane(R0 - 5);
        const bool rinA = (R0 >= 8) && cin;          // only R0==0 fails rows
        if (rinA) {
            const vf2* p1 = (const vf2*)(img1 + ibase + gc);
            const vf2* p2 = (const vf2*)(img2 + ibase + gc);
#pragma unroll
            for (int k = 0; k < 18; ++k) {
                const size_t off = (size_t)(jb + k) * (WW / 2);
                X[k] = p1[off];
                Y[k] = p2[off];
            }
        } else {
            const vf2* p1 = (const vf2*)(img1 + ibase + gcc);
            const vf2* p2 = (const vf2*)(img2 + ibase + gcc);
#pragma unroll
            for (int k = 0; k < 18; ++k) {
                const int j  = jb + k;
                const int jc = min(max(j, 0), HH - 1);
                const size_t off = (size_t)jc * (WW / 2);
                vf2 x = p1[off], y = p2[off];
                const bool ok = cok && ((unsigned)j < (unsigned)HH);
                if (!ok) { x = (vf2){0.f, 0.f}; y = (vf2){0.f, 0.f}; }
                X[k] = x; Y[k] = y;
            }
        }
        __builtin_amdgcn_sched_barrier(0);   // keep the 36-load burst batched

#pragma unroll
        for (int k = 0; k < 11; ++k) {
            const vf2 x = X[k], y = Y[k];
            const vf2 aa = x + y, dd = x - y;
            s1 += x; s2 += y;
            sp += aa * aa;
            sq += dd * dd;
        }
#pragma unroll
        for (int i = 0; i < 8; ++i) {
            if (i > 0) {
                const vf2 xn = X[10 + i], yn = Y[10 + i];
                const vf2 xo = X[i - 1],  yo = Y[i - 1];
                const vf2 an = xn + yn, dn = xn - yn;
                const vf2 ao = xo + yo, dq = xo - yo;
                s1 += xn - xo;
                s2 += yn - yo;
                sp += (an - ao) * (an + ao);
                sq += (dn - dq) * (dn + dq);
            }
            const h2 loa = __builtin_amdgcn_cvt_pkrtz(s1.x, s2.x);
            const h2 hia = __builtin_amdgcn_cvt_pkrtz(sp.x, sq.x);
            const h2 lob = __builtin_amdgcn_cvt_pkrtz(s1.y, s2.y);
            const h2 hib = __builtin_amdgcn_cvt_pkrtz(sp.y, sq.y);
            cs4[q][i][(2 * cg)     ^ i] = __builtin_shufflevector(loa, hia, 0, 1, 2, 3);
            cs4[q][i][(2 * cg + 1) ^ i] = __builtin_shufflevector(lob, hib, 0, 1, 2, 3);
        }
    }
    PHASE2;   // rows 0..7 (only X[7..14],Y[7..14] + sums stay live across this)

    // ================= Half B: colsum rows 8..15 (adds rows R0+13..R0+20) ===
    {
        vf2 Xn[8], Yn[8];
        const int jb2 = __builtin_amdgcn_readfirstlane(R0 + 13);
        const bool rinB = (R0 <= HH - 21) && cin;    // only R0==1008 fails rows
        if (rinB) {
            const vf2* p1 = (const vf2*)(img1 + ibase + gc);
            const vf2* p2 = (const vf2*)(img2 + ibase + gc);
#pragma unroll
            for (int k = 0; k < 8; ++k) {
                const size_t off = (size_t)(jb2 + k) * (WW / 2);
                Xn[k] = p1[off];
                Yn[k] = p2[off];
            }
        } else {
            const vf2* p1 = (const vf2*)(img1 + ibase + gcc);
            const vf2* p2 = (const vf2*)(img2 + ibase + gcc);
#pragma unroll
            for (int k = 0; k < 8; ++k) {
                const int j  = jb2 + k;
                const int jc = min(max(j, 0), HH - 1);
                const size_t off = (size_t)jc * (WW / 2);
                vf2 x = p1[off], y = p2[off];
                const bool ok = cok && ((unsigned)j < (unsigned)HH);
                if (!ok) { x = (vf2){0.f, 0.f}; y = (vf2){0.f, 0.f}; }
                Xn[k] = x; Yn[k] = y;
            }
        }
        __builtin_amdgcn_sched_barrier(0);   // keep the 16-load burst batched

        // continue sliding: row i adds Xn[i-8] (row R0+5+i), drops X[i-1]
#pragma unroll
        for (int i = 8; i < 16; ++i) {
            const vf2 xn = Xn[i - 8], yn = Yn[i - 8];
            const vf2 xo = X[i - 1],  yo = Y[i - 1];
            const vf2 an = xn + yn, dn = xn - yn;
            const vf2 ao = xo + yo, dq = xo - yo;
            s1 += xn - xo;
            s2 += yn - yo;
            sp += (an - ao) * (an + ao);
            sq += (dn - dq) * (dn + dq);
            const int i8 = i - 8;            // slab row 0..7
            const h2 loa = __builtin_amdgcn_cvt_pkrtz(s1.x, s2.x);
            const h2 hia = __builtin_amdgcn_cvt_pkrtz(sp.x, sq.x);
            const h2 lob = __builtin_amdgcn_cvt_pkrtz(s1.y, s2.y);
            const h2 hib = __builtin_amdgcn_cvt_pkrtz(sp.y, sq.y);
            cs4[q][i8][(2 * cg)     ^ i8] = __builtin_shufflevector(loa, hia, 0, 1, 2, 3);
            cs4[q][i8][(2 * cg + 1) ^ i8] = __builtin_shufflevector(lob, hib, 0, 1, 2, 3);
        }
    }
    PHASE2;   // rows 8..15

    // ---- wave reduction -> atomicAdd into spread slots ----
    float v = ssum;
#pragma unroll
    for (int off = 32; off > 0; off >>= 1) v += __shfl_down(v, off, 64);
    if (cg == 0) {
        const int bid = tx + 9 * (ty + 16 * b);
        atomicAdd(ws + ((bid * 4 + q) & (NSLOT - 1)), v);
    }
}

__global__ void ssim_fin(const float* __restrict__ ws, float* __restrict__ out, int ntot) {
    const int lane = threadIdx.x;        // 64 threads
    float v = 0.f;
#pragma unroll
    for (int k = 0; k < NSLOT / 64; ++k) v += ws[lane + 64 * k];
#pragma unroll
    for (int off = 32; off > 0; off >>= 1) v += __shfl_down(v, off, 64);
    if (lane == 0) out[0] = 1.f - v / (float)ntot;
}

extern "C" void kernel_launch(void* const* d_in, const int* in_sizes, int n_in,
                              void* d_out, int out_size, void* d_ws, size_t ws_size,
                              hipStream_t stream) {
    const float* img1 = (const float*)d_in[0];
    const float* img2 = (const float*)d_in[1];
    const float* win  = (const float*)d_in[2];
    float* out = (float*)d_out;
    float* ws  = (float*)d_ws;
    const int ntot = in_sizes[0];                       // 32*1024*1024
    const int batches = ntot / (HH * WW);               // 32

    ssim_ws_init<<<dim3(1), dim3(NSLOT), 0, stream>>>(ws);
    dim3 grid((WW + TW - 1) / TW, HH / 64, batches);    // 9 x 16 x 32
    ssim_main<<<grid, dim3(256), 0, stream>>>(img1, img2, win, ws);
    ssim_fin<<<dim3(1), dim3(64), 0, stream>>>(ws, out, ntot);
}

// Round 24
// 74.000 us; speedup vs baseline: 1.6679x; 1.6679x over previous
//
#include <hip/hip_runtime.h>

#define HH 1024
#define WW 1024
#define TW 116         // output cols per tile (even -> float2-aligned halo)
#define WLP 144        // colsum slots per row (max touched 141, no clamps)
#define NSLOT 1024     // partial-sum slots (atomic contention spread)
#define SSIM_C1 1e-4f
#define SSIM_C2 9e-4f

typedef float vf2 __attribute__((ext_vector_type(2)));
typedef __fp16 h2 __attribute__((ext_vector_type(2)));
typedef __fp16 h4 __attribute__((ext_vector_type(4)));

__global__ void ssim_ws_init(float* ws) { ws[threadIdx.x] = 0.f; }

// Wave-autonomous: each wave owns 8 output rows end-to-end (private LDS slab,
// no __syncthreads). Phase-2 peak live set kept at v[19] (38 VGPR) — R15/R18/
// R22/R23 lesson: anything bigger (or held across phase 2) spills at the
// (256,4) 128-VGPR cap and costs 100s of MB of scratch traffic.
__global__ __launch_bounds__(256, 4) void ssim_main(const float* __restrict__ img1,
                                                    const float* __restrict__ img2,
                                                    const float* __restrict__ window,
                                                    float* __restrict__ ws)
{
    __shared__ h4 cs4[4][8][WLP];    // 36.9 KB total; 8-row slab per wave

    const int tx = blockIdx.x;       // col tile: 0..8
    const int ty = blockIdx.y;       // 32-row band: 0..31
    const int b  = blockIdx.z;       // batch
    const int t  = threadIdx.x;
    const int q  = t >> 6;           // wave 0..3 -> rows 32*ty+8q .. +7
    const int cg = t & 63;
    const int C0 = tx * TW;
    const int R0 = ty * 32 + q * 8;
    const size_t ibase = (size_t)b * (size_t)(HH * WW);
    const float w = window[0];

    // ---- Phase 1 (wave-local): load 18 rows, vertical 11-sums, emit 8 rows ----
    {
        const int gc = C0 - 6 + 2 * cg;  // even -> 8B-aligned float2
        const int jb = __builtin_amdgcn_readfirstlane(R0 - 5);

        vf2 X[18], Y[18];
        const bool rin = (R0 >= 8) && (R0 <= HH - 16);   // jb>=0 && jb+17<HH
        const bool cin = (tx >= 1) && (tx <= 7);
        if (rin && cin) {
            const vf2* p1 = (const vf2*)(img1 + ibase + gc);
            const vf2* p2 = (const vf2*)(img2 + ibase + gc);
#pragma unroll
            for (int k = 0; k < 18; ++k) {
                const size_t off = (size_t)(jb + k) * (WW / 2);
                X[k] = p1[off];
                Y[k] = p2[off];
            }
        } else {
            const bool cok = (unsigned)gc < (unsigned)WW;
            const int gcc = min(max(gc, 0), WW - 2);
            const vf2* p1 = (const vf2*)(img1 + ibase + gcc);
            const vf2* p2 = (const vf2*)(img2 + ibase + gcc);
#pragma unroll
            for (int k = 0; k < 18; ++k) {
                const int j  = jb + k;
                const int jc = min(max(j, 0), HH - 1);
                const size_t off = (size_t)jc * (WW / 2);
                vf2 x = p1[off], y = p2[off];
                const bool ok = cok && ((unsigned)j < (unsigned)HH);
                if (!ok) { x = (vf2){0.f, 0.f}; y = (vf2){0.f, 0.f}; }
                X[k] = x; Y[k] = y;
            }
        }
        __builtin_amdgcn_sched_barrier(0);   // keep loads batched in flight

        vf2 s1 = {0.f, 0.f}, s2 = {0.f, 0.f}, sp = {0.f, 0.f}, sq = {0.f, 0.f};
#pragma unroll
        for (int k = 0; k < 11; ++k) {
            const vf2 x = X[k], y = Y[k];
            const vf2 aa = x + y, dd = x - y;
            s1 += x; s2 += y;
            sp += aa * aa;
            sq += dd * dd;
        }
#pragma unroll
        for (int i = 0; i < 8; ++i) {
            if (i > 0) {
                const vf2 xn = X[10 + i], yn = Y[10 + i];   // static idx
                const vf2 xo = X[i - 1],  yo = Y[i - 1];
                const vf2 an = xn + yn, dn = xn - yn;
                const vf2 ao = xo + yo, dq = xo - yo;
                s1 += xn - xo;
                s2 += yn - yo;
                sp += (an - ao) * (an + ao);
                sq += (dn - dq) * (dn + dq);
            }
            const h2 loa = __builtin_amdgcn_cvt_pkrtz(s1.x, s2.x);
            const h2 hia = __builtin_amdgcn_cvt_pkrtz(sp.x, sq.x);
            const h2 lob = __builtin_amdgcn_cvt_pkrtz(s1.y, s2.y);
            const h2 hib = __builtin_amdgcn_cvt_pkrtz(sp.y, sq.y);
            cs4[q][i][(2 * cg)     ^ i] = __builtin_shufflevector(loa, hia, 0, 1, 2, 3);
            cs4[q][i][(2 * cg + 1) ^ i] = __builtin_shufflevector(lob, hib, 0, 1, 2, 3);
        }
    }
    // NO __syncthreads: each wave reads only its own slab.

    // ---- Phase 2 (wave-local): lane = row(cg&7) x seg(cg>>3); 16 cols/lane as
    // two 8-col slides with win CARRIED across (end of slide 1 = slots
    // c0+9..c0+18 = exactly slide 2's prologue). Peak live set: v[19].
    // Raw-sum space: sigs = 0.5u(P+Q)-m11-m22, s12 = 0.25u(P-Q)-m12,
    // C1' = C1*u^2, C2' = C2*u^2 (u = 1/w).
    float ssum = 0.f;
    {
        const float u   = __builtin_amdgcn_rcpf(w);   // = 121
        const float hu  = 0.5f  * u;
        const float qu  = 0.25f * u;
        const float C1p = SSIM_C1 * u * u;
        const float C2p = SSIM_C2 * u * u;
        const int r   = cg & 7;
        const int seg = cg >> 3;             // 8 segments x 16 cols
        const int c0  = seg * 16;            // 0..112
        const int TWa = min(TW, WW - C0);    // ragged last col-tile (96)
        const int S   = min(16, TWa - c0);
        if (S > 0) {
            h4 v[19];
#pragma unroll
            for (int k = 0; k < 19; ++k)
                v[k] = cs4[q][r][(c0 + k) ^ r];   // max idx 130^7 <= 133 < 144
            __builtin_amdgcn_sched_barrier(0);    // keep 19 ds_reads batched

            h4 win = v[1] + v[2];
            win += v[3]; win += v[4]; win += v[5];
            win += v[6]; win += v[7]; win += v[8];
            win += v[9]; win += v[10];

            // slide 1: output cols c0+0 .. c0+7
#pragma unroll
            for (int p = 0; p < 8; ++p) {
                if (p >= S) break;
                win += v[p + 11];
                const float S1 = (float)win.x, S2 = (float)win.y;
                const float P  = (float)win.z, Q  = (float)win.w;
                const float m11 = S1 * S1, m22 = S2 * S2, m12 = S1 * S2;
                const float sigs = hu * (P + Q) - m11 - m22;
                const float s12  = qu * (P - Q) - m12;
                const float num  = (2.f * m12 + C1p) * (2.f * s12 + C2p);
                const float den  = (m11 + m22 + C1p) * (sigs + C2p);
                ssum += num * __builtin_amdgcn_rcpf(den);
                win -= v[p + 1];
            }
            // win now = slots c0+9 .. c0+18 (slide 2's prologue, free)

            // refill dead v[1..8] with slots c0+19 .. c0+26
#pragma unroll
            for (int k = 0; k < 8; ++k)
                v[k + 1] = cs4[q][r][(c0 + 19 + k) ^ r];  // max 138^7 <= 141 < 144
            __builtin_amdgcn_sched_barrier(0);

            // slide 2: output cols c0+8 .. c0+15
#pragma unroll
            for (int p = 0; p < 8; ++p) {
                if (p + 8 >= S) break;
                win += v[p + 1];                  // slot c0+19+p
                const float S1 = (float)win.x, S2 = (float)win.y;
                const float P  = (float)win.z, Q  = (float)win.w;
                const float m11 = S1 * S1, m22 = S2 * S2, m12 = S1 * S2;
                const float sigs = hu * (P + Q) - m11 - m22;
                const float s12  = qu * (P - Q) - m12;
                const float num  = (2.f * m12 + C1p) * (2.f * s12 + C2p);
                const float den  = (m11 + m22 + C1p) * (sigs + C2p);
                ssum += num * __builtin_amdgcn_rcpf(den);
                win -= v[p + 9];                  // slot c0+9+p
            }
        }
    }

    // ---- Per-wave reduction -> atomicAdd into spread slots ----
    float v = ssum;
#pragma unroll
    for (int off = 32; off > 0; off >>= 1) v += __shfl_down(v, off, 64);
    if (cg == 0) {
        const int bid  = tx + 9 * (ty + 32 * b);
        const int slot = (bid * 4 + q) & (NSLOT - 1);
        atomicAdd(ws + slot, v);
    }
}

__global__ void ssim_fin(const float* __restrict__ ws, float* __restrict__ out, int ntot) {
    const int lane = threadIdx.x;        // 64 threads
    float v = 0.f;
#pragma unroll
    for (int k = 0; k < NSLOT / 64; ++k) v += ws[lane + 64 * k];
#pragma unroll
    for (int off = 32; off > 0; off >>= 1) v += __shfl_down(v, off, 64);
    if (lane == 0) out[0] = 1.f - v / (float)ntot;
}

extern "C" void kernel_launch(void* const* d_in, const int* in_sizes, int n_in,
                              void* d_out, int out_size, void* d_ws, size_t ws_size,
                              hipStream_t stream) {
    const float* img1 = (const float*)d_in[0];
    const float* img2 = (const float*)d_in[1];
    const float* win  = (const float*)d_in[2];
    float* out = (float*)d_out;
    float* ws  = (float*)d_ws;
    const int ntot = in_sizes[0];                       // 32*1024*1024
    const int batches = ntot / (HH * WW);               // 32

    ssim_ws_init<<<dim3(1), dim3(NSLOT), 0, stream>>>(ws);
    dim3 grid((WW + TW - 1) / TW, HH / 32, batches);    // 9 x 32 x 32
    ssim_main<<<grid, dim3(256), 0, stream>>>(img1, img2, win, ws);
    ssim_fin<<<dim3(1), dim3(64), 0, stream>>>(ws, out, ntot);
}

// Round 25
// 72.423 us; speedup vs baseline: 1.7042x; 1.0218x over previous
//
#include <hip/hip_runtime.h>

#define HH 1024
#define WW 1024
#define TW 116         // output cols per tile (even -> float2-aligned halo)
#define WLP 144        // colsum slots per row (max touched 141, no clamps)
#define NSLOT 1024     // partial-sum slots (atomic contention spread)
#define NWG  (9 * 32 * 32)   // 9216 blocks; divisible by 8 XCDs -> clean swizzle
#define SSIM_C1 1e-4f
#define SSIM_C2 9e-4f

typedef float vf2 __attribute__((ext_vector_type(2)));
typedef __fp16 h2 __attribute__((ext_vector_type(2)));
typedef __fp16 h4 __attribute__((ext_vector_type(4)));

__global__ void ssim_ws_init(float* ws) { ws[threadIdx.x] = 0.f; }

// Wave-autonomous (R19 structure) + T1 XCD-aware block swizzle: HW assigns
// physical block n to XCD n%8; remap so each XCD owns a CONTIGUOUS 1/8 of the
// work grid -> vertical-halo neighbor bands (10 shared rows per 32) hit the
// same XCD's private L2 instead of crossing XCDs.
__global__ __launch_bounds__(256, 4) void ssim_main(const float* __restrict__ img1,
                                                    const float* __restrict__ img2,
                                                    const float* __restrict__ window,
                                                    float* __restrict__ ws)
{
    __shared__ h4 cs4[4][8][WLP];    // 36.9 KB total; 8-row slab per wave

    // XCD swizzle (bijective: NWG % 8 == 0)
    const int orig = blockIdx.x;
    const int swz  = (orig & 7) * (NWG >> 3) + (orig >> 3);
    const int tx   = swz % 9;        // col tile: 0..8
    const int rest = swz / 9;
    const int ty   = rest & 31;      // 32-row band: 0..31
    const int b    = rest >> 5;      // batch

    const int t  = threadIdx.x;
    const int q  = t >> 6;           // wave 0..3 -> rows 32*ty+8q .. +7
    const int cg = t & 63;
    const int C0 = tx * TW;
    const int R0 = ty * 32 + q * 8;
    const size_t ibase = (size_t)b * (size_t)(HH * WW);
    const float w = window[0];

    // ---- Phase 1 (wave-local): load 18 rows, vertical 11-sums, emit 8 rows ----
    {
        const int gc = C0 - 6 + 2 * cg;  // even -> 8B-aligned float2
        const int jb = __builtin_amdgcn_readfirstlane(R0 - 5);

        vf2 X[18], Y[18];
        const bool rin = (R0 >= 8) && (R0 <= HH - 16);   // jb>=0 && jb+17<HH
        const bool cin = (tx >= 1) && (tx <= 7);
        if (rin && cin) {
            const vf2* p1 = (const vf2*)(img1 + ibase + gc);
            const vf2* p2 = (const vf2*)(img2 + ibase + gc);
#pragma unroll
            for (int k = 0; k < 18; ++k) {
                const size_t off = (size_t)(jb + k) * (WW / 2);
                X[k] = p1[off];
                Y[k] = p2[off];
            }
        } else {
            const bool cok = (unsigned)gc < (unsigned)WW;
            const int gcc = min(max(gc, 0), WW - 2);
            const vf2* p1 = (const vf2*)(img1 + ibase + gcc);
            const vf2* p2 = (const vf2*)(img2 + ibase + gcc);
#pragma unroll
            for (int k = 0; k < 18; ++k) {
                const int j  = jb + k;
                const int jc = min(max(j, 0), HH - 1);
                const size_t off = (size_t)jc * (WW / 2);
                vf2 x = p1[off], y = p2[off];
                const bool ok = cok && ((unsigned)j < (unsigned)HH);
                if (!ok) { x = (vf2){0.f, 0.f}; y = (vf2){0.f, 0.f}; }
                X[k] = x; Y[k] = y;
            }
        }
        __builtin_amdgcn_sched_barrier(0);   // keep loads batched in flight

        vf2 s1 = {0.f, 0.f}, s2 = {0.f, 0.f}, sp = {0.f, 0.f}, sq = {0.f, 0.f};
#pragma unroll
        for (int k = 0; k < 11; ++k) {
            const vf2 x = X[k], y = Y[k];
            const vf2 aa = x + y, dd = x - y;
            s1 += x; s2 += y;
            sp += aa * aa;
            sq += dd * dd;
        }
#pragma unroll
        for (int i = 0; i < 8; ++i) {
            if (i > 0) {
                const vf2 xn = X[10 + i], yn = Y[10 + i];   // static idx
                const vf2 xo = X[i - 1],  yo = Y[i - 1];
                const vf2 an = xn + yn, dn = xn - yn;
                const vf2 ao = xo + yo, dq = xo - yo;
                s1 += xn - xo;
                s2 += yn - yo;
                sp += (an - ao) * (an + ao);
                sq += (dn - dq) * (dn + dq);
            }
            const h2 loa = __builtin_amdgcn_cvt_pkrtz(s1.x, s2.x);
            const h2 hia = __builtin_amdgcn_cvt_pkrtz(sp.x, sq.x);
            const h2 lob = __builtin_amdgcn_cvt_pkrtz(s1.y, s2.y);
            const h2 hib = __builtin_amdgcn_cvt_pkrtz(sp.y, sq.y);
            cs4[q][i][(2 * cg)     ^ i] = __builtin_shufflevector(loa, hia, 0, 1, 2, 3);
            cs4[q][i][(2 * cg + 1) ^ i] = __builtin_shufflevector(lob, hib, 0, 1, 2, 3);
        }
    }
    // NO __syncthreads: each wave reads only its own slab.

    // ---- Phase 2 (wave-local): lane = row(cg&7) x seg(cg>>3); 16 cols/lane as
    // two 8-col slides with win CARRIED across. Peak live set: v[19].
    // Raw-sum space: sigs = 0.5u(P+Q)-m11-m22, s12 = 0.25u(P-Q)-m12,
    // C1' = C1*u^2, C2' = C2*u^2 (u = 1/w).
    float ssum = 0.f;
    {
        const float u   = __builtin_amdgcn_rcpf(w);   // = 121
        const float hu  = 0.5f  * u;
        const float qu  = 0.25f * u;
        const float C1p = SSIM_C1 * u * u;
        const float C2p = SSIM_C2 * u * u;
        const int r   = cg & 7;
        const int seg = cg >> 3;             // 8 segments x 16 cols
        const int c0  = seg * 16;            // 0..112
        const int TWa = min(TW, WW - C0);    // ragged last col-tile (96)
        const int S   = min(16, TWa - c0);
        if (S > 0) {
            h4 v[19];
#pragma unroll
            for (int k = 0; k < 19; ++k)
                v[k] = cs4[q][r][(c0 + k) ^ r];   // max idx 130^7 <= 133 < 144
            __builtin_amdgcn_sched_barrier(0);    // keep 19 ds_reads batched

            h4 win = v[1] + v[2];
            win += v[3]; win += v[4]; win += v[5];
            win += v[6]; win += v[7]; win += v[8];
            win += v[9]; win += v[10];

            // slide 1: output cols c0+0 .. c0+7
#pragma unroll
            for (int p = 0; p < 8; ++p) {
                if (p >= S) break;
                win += v[p + 11];
                const float S1 = (float)win.x, S2 = (float)win.y;
                const float P  = (float)win.z, Q  = (float)win.w;
                const float m11 = S1 * S1, m22 = S2 * S2, m12 = S1 * S2;
                const float sigs = hu * (P + Q) - m11 - m22;
                const float s12  = qu * (P - Q) - m12;
                const float num  = (2.f * m12 + C1p) * (2.f * s12 + C2p);
                const float den  = (m11 + m22 + C1p) * (sigs + C2p);
                ssum += num * __builtin_amdgcn_rcpf(den);
                win -= v[p + 1];
            }
            // win now = slots c0+9 .. c0+18 (slide 2's prologue, free)

            // refill dead v[1..8] with slots c0+19 .. c0+26
#pragma unroll
            for (int k = 0; k < 8; ++k)
                v[k + 1] = cs4[q][r][(c0 + 19 + k) ^ r];  // max 138^7 <= 141 < 144
            __builtin_amdgcn_sched_barrier(0);

            // slide 2: output cols c0+8 .. c0+15
#pragma unroll
            for (int p = 0; p < 8; ++p) {
                if (p + 8 >= S) break;
                win += v[p + 1];                  // slot c0+19+p
                const float S1 = (float)win.x, S2 = (float)win.y;
                const float P  = (float)win.z, Q  = (float)win.w;
                const float m11 = S1 * S1, m22 = S2 * S2, m12 = S1 * S2;
                const float sigs = hu * (P + Q) - m11 - m22;
                const float s12  = qu * (P - Q) - m12;
                const float num  = (2.f * m12 + C1p) * (2.f * s12 + C2p);
                const float den  = (m11 + m22 + C1p) * (sigs + C2p);
                ssum += num * __builtin_amdgcn_rcpf(den);
                win -= v[p + 9];                  // slot c0+9+p
            }
        }
    }

    // ---- Per-wave reduction -> atomicAdd into spread slots ----
    float v = ssum;
#pragma unroll
    for (int off = 32; off > 0; off >>= 1) v += __shfl_down(v, off, 64);
    if (cg == 0) {
        const int slot = (swz * 4 + q) & (NSLOT - 1);
        atomicAdd(ws + slot, v);
    }
}

__global__ void ssim_fin(const float* __restrict__ ws, float* __restrict__ out, int ntot) {
    const int lane = threadIdx.x;        // 64 threads
    float v = 0.f;
#pragma unroll
    for (int k = 0; k < NSLOT / 64; ++k) v += ws[lane + 64 * k];
#pragma unroll
    for (int off = 32; off > 0; off >>= 1) v += __shfl_down(v, off, 64);
    if (lane == 0) out[0] = 1.f - v / (float)ntot;
}

extern "C" void kernel_launch(void* const* d_in, const int* in_sizes, int n_in,
                              void* d_out, int out_size, void* d_ws, size_t ws_size,
                              hipStream_t stream) {
    const float* img1 = (const float*)d_in[0];
    const float* img2 = (const float*)d_in[1];
    const float* win  = (const float*)d_in[2];
    float* out = (float*)d_out;
    float* ws  = (float*)d_ws;
    const int ntot = in_sizes[0];                       // 32*1024*1024
    ssim_ws_init<<<dim3(1), dim3(NSLOT), 0, stream>>>(ws);
    ssim_main<<<dim3(NWG), dim3(256), 0, stream>>>(img1, img2, win, ws);
    ssim_fin<<<dim3(1), dim3(64), 0, stream>>>(ws, out, ntot);
}